// Round 1
// baseline (416.295 us; speedup 1.0000x reference)
//
#include <hip/hip_runtime.h>
#include <hip/hip_bf16.h>
#include <hip/hip_fp16.h>

typedef _Float16 f16;
typedef _Float16 f16x8 __attribute__((ext_vector_type(8)));
typedef float f32x4 __attribute__((ext_vector_type(4)));

#define SP 16384  // 128*128 spatial per batch

// ---- transpose + cast weights to fp16, N-major: WT[n][k] = W[k][n] ----
__global__ void prep_weights(const float* __restrict__ Wq,
                             const float* __restrict__ Wkv,
                             const float* __restrict__ Wp,
                             f16* __restrict__ wqT,
                             f16* __restrict__ wkvT,
                             f16* __restrict__ wpT) {
  const int f = threadIdx.x;  // 0..511 feature (col of W)
  const int k = blockIdx.x;   // 0..255 input dim (row of W)
  wkvT[f * 256 + k] = (f16)Wkv[k * 512 + f];
  if (f < 256) {
    wqT[f * 256 + k] = (f16)Wq[k * 256 + f];
    wpT[f * 256 + k] = (f16)Wp[k * 256 + f];
  }
}

// Fused: stage x -> q/k/v GEMMs (fp16 MFMA, fp32 acc) -> softmax-attn -> proj -> out
__global__ __launch_bounds__(512, 2) void fused_attn(
    const float* __restrict__ x,
    const float* __restrict__ bq,
    const float* __restrict__ bkv,
    const float* __restrict__ bp,
    const float* __restrict__ pos_bias,
    const f16* __restrict__ wqT,
    const f16* __restrict__ wkvT,
    const f16* __restrict__ wpT,
    float* __restrict__ out) {
  // 5 t-tiles of [16 rows][256 d] fp16, XOR-swizzled: byte ^= (row&7)<<4
  __shared__ f16 xs[5 * 16 * 256];  // 40 KB

  const int tid = threadIdx.x;
  const int blk = blockIdx.x;
  const int b  = blk >> 10;         // batch
  const int s0 = (blk & 1023) << 4; // spatial tile base (16 rows)

  // ---- stage x tile ----
  {
    const int row = tid & 15;
    const int grp = tid >> 4;  // 0..31
    const float* xb = x + (size_t)b * (5 * 256 * SP) + s0 + row;
    char* lw = (char*)xs;
#pragma unroll
    for (int it = 0; it < 40; ++it) {
      const int p = grp + (it << 5);  // (t,d) pair id 0..1279
      const int t = p >> 8;
      const int d = p & 255;
      const float v = xb[(size_t)(t * 256 + d) * SP];
      const int byte = (t << 13) + ((((row << 9) + (d << 1))) ^ ((row & 7) << 4));
      *(f16*)(lw + byte) = (f16)v;
    }
  }
  __syncthreads();

  const int lane = tid & 63;
  const int w = tid >> 6;    // wave 0..7 -> heads 2w, 2w+1
  const int c = lane & 15;   // A-row / B-col / C-col
  const int g = lane >> 4;   // 0..3 (k-group; C rows 4g..4g+3)
  const int hA = 2 * w;

  f32x4 qacc[2] = {};
  f32x4 kacc[2][5] = {};
  f32x4 vacc[2][5] = {};
  const char* lr = (const char*)xs;

  const f16* wqp0 = wqT + (hA * 16 + c) * 256;
  const f16* wqp1 = wqT + ((hA + 1) * 16 + c) * 256;
  const f16* wkp0 = wkvT + (hA * 16 + c) * 256;
  const f16* wkp1 = wkvT + ((hA + 1) * 16 + c) * 256;
  const f16* wvp0 = wkvT + (256 + hA * 16 + c) * 256;
  const f16* wvp1 = wkvT + (256 + (hA + 1) * 16 + c) * 256;

  for (int k0 = 0; k0 < 8; ++k0) {
    const int kk = (k0 << 5) + (g << 3);  // k base for this lane
    f16x8 a[5];
#pragma unroll
    for (int t = 0; t < 5; ++t) {
      const int byte = (t << 13) + ((((c << 9) + (kk << 1))) ^ ((c & 7) << 4));
      a[t] = *(const f16x8*)(lr + byte);
    }
    const f16x8 fq0 = *(const f16x8*)(wqp0 + kk);
    const f16x8 fq1 = *(const f16x8*)(wqp1 + kk);
    const f16x8 fk0 = *(const f16x8*)(wkp0 + kk);
    const f16x8 fk1 = *(const f16x8*)(wkp1 + kk);
    const f16x8 fv0 = *(const f16x8*)(wvp0 + kk);
    const f16x8 fv1 = *(const f16x8*)(wvp1 + kk);

    qacc[0] = __builtin_amdgcn_mfma_f32_16x16x32_f16(a[0], fq0, qacc[0], 0, 0, 0);
    qacc[1] = __builtin_amdgcn_mfma_f32_16x16x32_f16(a[0], fq1, qacc[1], 0, 0, 0);
#pragma unroll
    for (int t = 0; t < 5; ++t) {
      kacc[0][t] = __builtin_amdgcn_mfma_f32_16x16x32_f16(a[t], fk0, kacc[0][t], 0, 0, 0);
      kacc[1][t] = __builtin_amdgcn_mfma_f32_16x16x32_f16(a[t], fk1, kacc[1][t], 0, 0, 0);
      vacc[0][t] = __builtin_amdgcn_mfma_f32_16x16x32_f16(a[t], fv0, vacc[0][t], 0, 0, 0);
      vacc[1][t] = __builtin_amdgcn_mfma_f32_16x16x32_f16(a[t], fv1, vacc[1][t], 0, 0, 0);
    }
  }

  // ---- attention (all in-register; C layout: col=c, rows 4g+r) ----
  f32x4 aout[2];
#pragma unroll
  for (int j = 0; j < 2; ++j) {
    const int hj = hA + j;
    const float bqv = bq[hj * 16 + c];
    const float bkk = bkv[hj * 16 + c];
    const float bvv = bkv[256 + hj * 16 + c];

    f32x4 q4 = qacc[j];
#pragma unroll
    for (int r = 0; r < 4; ++r) q4[r] += bqv;

    f32x4 s[5];
#pragma unroll
    for (int t = 0; t < 5; ++t) {
      f32x4 k4 = kacc[j][t];
#pragma unroll
      for (int r = 0; r < 4; ++r) k4[r] += bkk;
      f32x4 p = q4 * k4;
      const float pb = pos_bias[hj * 5 + t];
#pragma unroll
      for (int r = 0; r < 4; ++r) {
        float v = p[r];
        v += __shfl_xor(v, 1);
        v += __shfl_xor(v, 2);
        v += __shfl_xor(v, 4);
        v += __shfl_xor(v, 8);
        s[t][r] = v * 4.0f + pb;  // / temperature (=0.25) then + pos_bias
      }
    }
    f32x4 m = s[0];
#pragma unroll
    for (int t = 1; t < 5; ++t)
#pragma unroll
      for (int r = 0; r < 4; ++r) m[r] = fmaxf(m[r], s[t][r]);
    f32x4 lsum = {};
#pragma unroll
    for (int t = 0; t < 5; ++t)
#pragma unroll
      for (int r = 0; r < 4; ++r) { s[t][r] = __expf(s[t][r] - m[r]); lsum[r] += s[t][r]; }
    f32x4 inv;
#pragma unroll
    for (int r = 0; r < 4; ++r) inv[r] = 1.0f / lsum[r];
    f32x4 o = {};
#pragma unroll
    for (int t = 0; t < 5; ++t)
#pragma unroll
      for (int r = 0; r < 4; ++r) o[r] += s[t][r] * inv[r] * (vacc[j][t][r] + bvv);
    aout[j] = o;
  }

  __syncthreads();  // all xs reads done before overwriting with attn_out

  // ---- attn_out [16][256] fp16 -> LDS (same swizzle) ----
  {
    char* lw = (char*)xs;
#pragma unroll
    for (int j = 0; j < 2; ++j) {
      const int feat = (hA + j) * 16 + c;
#pragma unroll
      for (int r = 0; r < 4; ++r) {
        const int row = (g << 2) + r;
        const int byte = (((row << 9) + (feat << 1))) ^ ((row & 7) << 4);
        *(f16*)(lw + byte) = (f16)aout[j][r];
      }
    }
  }
  __syncthreads();

  // ---- final projection: attn_out[16x256] @ Wp[256x256] ----
  f32x4 facc[2] = {};
  const f16* wpp0 = wpT + (hA * 16 + c) * 256;
  const f16* wpp1 = wpT + ((hA + 1) * 16 + c) * 256;
  for (int k0 = 0; k0 < 8; ++k0) {
    const int kk = (k0 << 5) + (g << 3);
    const int byte = (((c << 9) + (kk << 1))) ^ ((c & 7) << 4);
    const f16x8 af = *(const f16x8*)(lr + byte);
    const f16x8 f0 = *(const f16x8*)(wpp0 + kk);
    const f16x8 f1 = *(const f16x8*)(wpp1 + kk);
    facc[0] = __builtin_amdgcn_mfma_f32_16x16x32_f16(af, f0, facc[0], 0, 0, 0);
    facc[1] = __builtin_amdgcn_mfma_f32_16x16x32_f16(af, f1, facc[1], 0, 0, 0);
  }

  // ---- store: out[b, dg, s0 + 4g + r], 4 consecutive spatial per lane ----
#pragma unroll
  for (int j = 0; j < 2; ++j) {
    const int dg = (hA + j) * 16 + c;
    const float bias = bp[dg];
    f32x4 vs = facc[j];
#pragma unroll
    for (int r = 0; r < 4; ++r) vs[r] += bias;
    float* dst = out + ((size_t)b * 256 + dg) * SP + s0 + (g << 2);
    *(f32x4*)dst = vs;
  }
}

extern "C" void kernel_launch(void* const* d_in, const int* in_sizes, int n_in,
                              void* d_out, int out_size, void* d_ws, size_t ws_size,
                              hipStream_t stream) {
  const float* x   = (const float*)d_in[0];
  const float* Wq  = (const float*)d_in[1];
  const float* bq  = (const float*)d_in[2];
  const float* Wkv = (const float*)d_in[3];
  const float* bkv = (const float*)d_in[4];
  const float* Wp  = (const float*)d_in[5];
  const float* bp  = (const float*)d_in[6];
  const float* pos = (const float*)d_in[7];

  f16* wqT  = (f16*)d_ws;            // 256*256
  f16* wkvT = wqT + 256 * 256;       // 512*256
  f16* wpT  = wkvT + 512 * 256;      // 256*256

  prep_weights<<<256, 512, 0, stream>>>(Wq, Wkv, Wp, wqT, wkvT, wpT);
  fused_attn<<<4096, 512, 0, stream>>>(x, bq, bkv, bp, pos, wqT, wkvT, wpT,
                                       (float*)d_out);
}